// Round 12
// baseline (259.252 us; speedup 1.0000x reference)
//
#include <hip/hip_runtime.h>
#include <hip/hip_bf16.h>
#include <stdint.h>

#define SEQ 2048
#define BAT 32
#define EDIM 1024
#define MROWS (SEQ*BAT)   // 65536

typedef __bf16 bf16x8 __attribute__((ext_vector_type(8)));
typedef float f32x4 __attribute__((ext_vector_type(4)));
typedef unsigned short u16x8 __attribute__((ext_vector_type(8)));

typedef __attribute__((address_space(3))) unsigned int lds_uint;
typedef const __attribute__((address_space(1))) unsigned int glb_uint;

__device__ __forceinline__ void async16(void* lds, const void* g) {
  __builtin_amdgcn_global_load_lds((glb_uint*)g, (lds_uint*)lds, 16, 0, 0);
}

// hardware cvt (RNE): compiler emits v_cvt_pk_bf16_f32 pairs
__device__ __forceinline__ u16x8 cvt8(float4 a, float4 b) {
  bf16x8 r;
  r[0] = (__bf16)a.x; r[1] = (__bf16)a.y; r[2] = (__bf16)a.z; r[3] = (__bf16)a.w;
  r[4] = (__bf16)b.x; r[5] = (__bf16)b.y; r[6] = (__bf16)b.z; r[7] = (__bf16)b.w;
  return __builtin_bit_cast(u16x8, r);
}

// fast tanh: (e^{2x}-1)/(e^{2x}+1), clamped; ~7 VALU ops vs ~25 for ocml tanhf
__device__ __forceinline__ float fast_tanh(float x) {
  float xc = fminf(fmaxf(x, -9.f), 9.f);
  float e = __expf(2.f * xc);
  return (e - 1.f) * __builtin_amdgcn_rcpf(e + 1.f);
}

// ---------------- Kernel PRE: fused {Wv cvt | nv | pqb} by blockIdx role ----------
__global__ void k_pre(const float* __restrict__ Wv, unsigned short* __restrict__ Wvb,
                      const float* __restrict__ v, const float* __restrict__ g,
                      float* __restrict__ nv,
                      const float* __restrict__ query, const float* __restrict__ Wq,
                      const float* __restrict__ bias, float* __restrict__ pqb) {
  const int bid = blockIdx.x;
  const int t = threadIdx.x;

  if (bid < 512) {                      // ---- Wv convert ----
    long long i = (long long)bid * 256 + t;   // 131072 chunks of 8
    const float4* p = reinterpret_cast<const float4*>(Wv + i * 8);
    *reinterpret_cast<u16x8*>(Wvb + i * 8) = cvt8(p[0], p[1]);
    return;
  }

  if (bid == 512) {                     // ---- nv ----
    __shared__ float red[256];
    float s = 0.f;
    for (int i = t; i < EDIM; i += 256) { float x = v[i]; s += x * x; }
    red[t] = s; __syncthreads();
    for (int o = 128; o > 0; o >>= 1) {
      if (t < o) red[t] += red[t + o];
      __syncthreads();
    }
    float scale = g[0] / sqrtf(red[0]);
    for (int i = t; i < EDIM; i += 256) nv[i] = v[i] * scale;
    return;
  }

  // ---- pqb ----
  __shared__ float wq[1024];
  const int e = bid - 513;
  reinterpret_cast<float4*>(wq)[t] =
      reinterpret_cast<const float4*>(Wq + (size_t)e * EDIM)[t];
  __syncthreads();
  int w = t >> 6, lane = t & 63;
  float be = bias[e];
  for (int bb = 0; bb < 8; ++bb) {
    int b_ = w * 8 + bb;
    const float4* q4 = reinterpret_cast<const float4*>(query + (size_t)b_ * EDIM) + lane * 4;
    const float4* w4 = reinterpret_cast<const float4*>(wq) + lane * 4;
    float s = 0.f;
#pragma unroll
    for (int jj = 0; jj < 4; ++jj) {
      float4 a = q4[jj], c = w4[jj];
      s += a.x * c.x + a.y * c.y + a.z * c.z + a.w * c.w;
    }
#pragma unroll
    for (int m = 32; m > 0; m >>= 1) s += __shfl_xor(s, m);
    if (lane == 0) pqb[(size_t)b_ * EDIM + e] = s + be;
  }
}

// ---------------- Kernel D: 256x256-tile pipelined GEMM, in-kernel fp32->bf16 A ----
// R9 base + rotated A-half pipeline: h0 of tile t+2 is issued PRE-barrier so its
// HBM latency is absorbed by the barrier's existing vmcnt(0) drain; carried in
// ar[] across the barrier and written after kk=0 with ~full-body cover.
__global__ __launch_bounds__(512, 1) void k_gemm(
    const float* __restrict__ value,        // [MROWS][1024] fp32
    const unsigned short* __restrict__ Bm,  // [1024][1024] bf16 bits
    const float* __restrict__ pqb,          // [32][1024]
    const float* __restrict__ nv,           // [1024]
    float* __restrict__ part)               // [4][MROWS]
{
  __shared__ char smem[2 * 65536 + 4 * 256 * 4];

  const int tid = threadIdx.x;
  const int lane = tid & 63;
  const int wid = tid >> 6;
  const int wm = wid >> 2;                  // 0..1
  const int wn = wid & 3;                   // 0..3

  const int bid = blockIdx.x;               // 0..1023
  const int xcd = bid & 7;
  const int j = bid >> 3;                   // 0..127
  const int mi_blk = xcd * 32 + (j >> 2);
  const int ni_blk = j & 3;
  const size_t m0 = (size_t)mi_blk * 256;
  const int n0 = ni_blk * 256;

  float* partLds = (float*)(smem + 131072);

  f32x4 acc[8][4];
#pragma unroll
  for (int i = 0; i < 8; ++i)
#pragma unroll
    for (int jj = 0; jj < 4; ++jj) acc[i][jj] = f32x4{0.f, 0.f, 0.f, 0.f};

  // ---- A staging (fp32 -> reg -> cvt -> swizzled ds_write), 2 halves ----
  const int csrc = (tid & 7) ^ ((tid >> 3) & 7);
  const int rowt = tid >> 3;                // 0..63
  const float* gvA[4];
#pragma unroll
  for (int i = 0; i < 4; ++i)
    gvA[i] = value + (m0 + (size_t)(i * 64 + rowt)) * 1024 + (tid & 7) * 8;
  const int dstA0 = rowt * 128 + csrc * 16;  // + c*8192 per chunk

  float4 ar[4];   // ONE shared 16-VGPR staging block; WAR dep stops overlap

  auto loadAh = [&](int h) {
#pragma unroll
    for (int i = 0; i < 2; ++i) {
      int c = 2 * h + i;
      ar[2 * i]     = *reinterpret_cast<const float4*>(gvA[c]);
      ar[2 * i + 1] = *reinterpret_cast<const float4*>(gvA[c] + 4);
      gvA[c] += 64;
    }
  };
  auto writeAh = [&](char* nb, int h) {
#pragma unroll
    for (int i = 0; i < 2; ++i) {
      int c = 2 * h + i;
      *reinterpret_cast<u16x8*>(nb + c * 8192 + dstA0) = cvt8(ar[2 * i], ar[2 * i + 1]);
    }
  };

  // ---- B staging (async16, inverse-swizzled source) ----
  const unsigned short* gB[4];
#pragma unroll
  for (int i = 0; i < 4; ++i)
    gB[i] = Bm + (size_t)(n0 + i * 64 + rowt) * 1024 + csrc * 8;
  const int ldsOffB = 32768 + tid * 16;
  auto stageB = [&](char* sl) {
#pragma unroll
    for (int i = 0; i < 4; ++i) {
      async16(sl + ldsOffB + i * 8192, gB[i]);
      gB[i] += 64;
    }
  };

  // ---- LDS read addressing (conflict-free) ----
  const int rA = lane & 15;
  const int cs0 = (lane >> 4) ^ (lane & 7);
  const int cs1 = cs0 ^ 4;

  char* buf0 = smem;
  char* buf1 = smem + 65536;

  // prologue: tile 0 into buf0, then pre-issue h0 of tile 1 (drained at barrier)
  loadAh(0);
  stageB(buf0);
  writeAh(buf0, 0);
  loadAh(1);
  writeAh(buf0, 1);
  loadAh(0);                   // h0 of tile 1 -> carried in ar across the barrier
  __syncthreads();

  // body(t): compute cb=tile t; fill nb=tile t+1 (pf); pre-issue h0 of t+2 (pfn).
  // On entry (pf): ar holds h0 of tile t+1, loaded a full body ago -> no stall.
  auto body = [&](char* cb, char* nb, bool pf, bool pfn) {
    // ---- kk = 0 ----
    {
      bf16x8 af[8], bf[4];
#pragma unroll
      for (int mi = 0; mi < 8; ++mi)
        af[mi] = *reinterpret_cast<const bf16x8*>(
            cb + (wm * 128 + mi * 16 + rA) * 128 + cs0 * 16);
#pragma unroll
      for (int nj = 0; nj < 2; ++nj)
        bf[nj] = *reinterpret_cast<const bf16x8*>(
            cb + 32768 + (wn * 64 + nj * 16 + rA) * 128 + cs0 * 16);

      __builtin_amdgcn_s_setprio(1);
#pragma unroll
      for (int mi = 0; mi < 8; ++mi)
#pragma unroll
        for (int nj = 0; nj < 2; ++nj)
          acc[mi][nj] = __builtin_amdgcn_mfma_f32_16x16x32_bf16(af[mi], bf[nj], acc[mi][nj], 0, 0, 0);
      __builtin_amdgcn_s_setprio(0);

      if (pf) stageB(nb);

#pragma unroll
      for (int nj = 2; nj < 4; ++nj)
        bf[nj] = *reinterpret_cast<const bf16x8*>(
            cb + 32768 + (wn * 64 + nj * 16 + rA) * 128 + cs0 * 16);

      __builtin_amdgcn_s_setprio(1);
#pragma unroll
      for (int mi = 0; mi < 8; ++mi)
#pragma unroll
        for (int nj = 2; nj < 4; ++nj)
          acc[mi][nj] = __builtin_amdgcn_mfma_f32_16x16x32_bf16(af[mi], bf[nj], acc[mi][nj], 0, 0, 0);
      __builtin_amdgcn_s_setprio(0);
    }

    if (pf) {
      writeAh(nb, 0);           // h0: loaded pre-barrier last body -> latency long gone
      loadAh(1);                // h1 of tile t+1 (reuses ar; WAR ordered)
    }

    // ---- kk = 1 ----
    {
      bf16x8 af[8], bf[4];
#pragma unroll
      for (int mi = 0; mi < 8; ++mi)
        af[mi] = *reinterpret_cast<const bf16x8*>(
            cb + (wm * 128 + mi * 16 + rA) * 128 + cs1 * 16);
#pragma unroll
      for (int nj = 0; nj < 2; ++nj)
        bf[nj] = *reinterpret_cast<const bf16x8*>(
            cb + 32768 + (wn * 64 + nj * 16 + rA) * 128 + cs1 * 16);

      __builtin_amdgcn_s_setprio(1);
#pragma unroll
      for (int mi = 0; mi < 8; ++mi)
#pragma unroll
        for (int nj = 0; nj < 2; ++nj)
          acc[mi][nj] = __builtin_amdgcn_mfma_f32_16x16x32_bf16(af[mi], bf[nj], acc[mi][nj], 0, 0, 0);
      __builtin_amdgcn_s_setprio(0);

#pragma unroll
      for (int nj = 2; nj < 4; ++nj)
        bf[nj] = *reinterpret_cast<const bf16x8*>(
            cb + 32768 + (wn * 64 + nj * 16 + rA) * 128 + cs1 * 16);

      __builtin_amdgcn_s_setprio(1);
#pragma unroll
      for (int mi = 0; mi < 8; ++mi)
#pragma unroll
        for (int nj = 2; nj < 4; ++nj)
          acc[mi][nj] = __builtin_amdgcn_mfma_f32_16x16x32_bf16(af[mi], bf[nj], acc[mi][nj], 0, 0, 0);
      __builtin_amdgcn_s_setprio(0);
    }

    if (pf) writeAh(nb, 1);     // h1: ~1 MFMA-cluster cover (short, unavoidable)
    if (pfn) loadAh(0);         // h0 of tile t+2: drained by the barrier below
    __syncthreads();
  };

#pragma unroll 1
  for (int tt = 0; tt < 8; ++tt) {
    body(buf0, buf1, true, tt < 7);       // t = 2tt   (pfn: t+2 <= 15)
    body(buf1, buf0, tt < 7, tt < 7);     // t = 2tt+1
  }

  // Epilogue
  const int cgrp = lane >> 4;
  const int ccol = lane & 15;
  float nve[4];
#pragma unroll
  for (int nj = 0; nj < 4; ++nj) nve[nj] = nv[n0 + wn * 64 + nj * 16 + ccol];

#pragma unroll
  for (int mi = 0; mi < 8; ++mi) {
#pragma unroll
    for (int r = 0; r < 4; ++r) {
      int rloc = wm * 128 + mi * 16 + cgrp * 4 + r;
      int b_ = rloc & 31;
      const float* pq = pqb + (size_t)b_ * EDIM + n0 + wn * 64 + ccol;
      float s = 0.f;
#pragma unroll
      for (int nj = 0; nj < 4; ++nj)
        s += nve[nj] * fast_tanh(acc[mi][nj][r] + pq[nj * 16]);
      s += __shfl_xor(s, 1);
      s += __shfl_xor(s, 2);
      s += __shfl_xor(s, 4);
      s += __shfl_xor(s, 8);
      if (ccol == 0) partLds[wn * 256 + rloc] = s;
    }
  }
  __syncthreads();
  if (tid < 256)
    part[(size_t)ni_blk * MROWS + m0 + tid] =
        partLds[tid] + partLds[256 + tid] + partLds[512 + tid] + partLds[768 + tid];
}

// ---------------- Kernel E: reduce 4 chunks + mask + softmax over s ----------------
__global__ void k_softmax(const float* __restrict__ part,          // [4][MROWS]
                          const unsigned char* __restrict__ mask,  // [S][B]
                          float* __restrict__ scores,              // [MROWS]
                          float* __restrict__ out_attn)            // d_out + 32768
{
  int b_ = blockIdx.x;
  int t = threadIdx.x;
  __shared__ float red[256];
  float sc[8];
  float mx = -1e30f;
#pragma unroll
  for (int i = 0; i < 8; ++i) {
    int s_ = t + i * 256;
    size_t r = (size_t)s_ * BAT + b_;
    float v = 0.f;
#pragma unroll
    for (int c = 0; c < 4; ++c) v += part[(size_t)c * MROWS + r];
    if (mask[r]) v = -1e30f;
    sc[i] = v;
    mx = fmaxf(mx, v);
  }
  red[t] = mx; __syncthreads();
  for (int o = 128; o > 0; o >>= 1) {
    if (t < o) red[t] = fmaxf(red[t], red[t + o]);
    __syncthreads();
  }
  mx = red[0];
  __syncthreads();
  float sum = 0.f;
#pragma unroll
  for (int i = 0; i < 8; ++i) { sc[i] = expf(sc[i] - mx); sum += sc[i]; }
  red[t] = sum; __syncthreads();
  for (int o = 128; o > 0; o >>= 1) {
    if (t < o) red[t] += red[t + o];
    __syncthreads();
  }
  float inv = 1.f / red[0];
#pragma unroll
  for (int i = 0; i < 8; ++i) {
    int s_ = t + i * 256;
    size_t r = (size_t)s_ * BAT + b_;
    float w = sc[i] * inv;
    scores[r] = w;
    out_attn[r] = w;
    out_attn[MROWS + r] = w;
  }
}

// ---------------- Kernel F: context partials (fp32 value, L3-resident) ----------
__global__ void k_ctx(const float* __restrict__ value,   // [MROWS][1024] fp32
                      const float* __restrict__ scores,  // [MROWS]
                      float* __restrict__ pctx)          // [32][BAT][1024]
{
  int b_ = blockIdx.x;   // 0..31
  int sch = blockIdx.y;  // 0..15
  int t = threadIdx.x;
  int d8 = t & 127;
  int sr = t >> 7;       // 0..1
  float acc[8];
#pragma unroll
  for (int j = 0; j < 8; ++j) acc[j] = 0.f;
  int s0 = sch * 128;
  for (int i = 0; i < 64; ++i) {
    int s_ = s0 + i * 2 + sr;
    size_t r = (size_t)s_ * BAT + b_;
    float w = scores[r];
    const float4* p = reinterpret_cast<const float4*>(value + r * 1024 + d8 * 8);
    float4 a = p[0], b = p[1];
    acc[0] += w * a.x; acc[1] += w * a.y; acc[2] += w * a.z; acc[3] += w * a.w;
    acc[4] += w * b.x; acc[5] += w * b.y; acc[6] += w * b.z; acc[7] += w * b.w;
  }
  float* dst = pctx + ((size_t)(sch * 2 + sr) * BAT + b_) * 1024 + d8 * 8;
#pragma unroll
  for (int j = 0; j < 8; ++j) dst[j] = acc[j];
}

// ---------------- Kernel G: final context reduce (32 chunks) ----------------
__global__ void k_ctx_reduce(const float* __restrict__ pctx, float* __restrict__ out) {
  int i = blockIdx.x * 256 + threadIdx.x;  // 0..32767
  float s = 0.f;
#pragma unroll
  for (int c = 0; c < 32; ++c) s += pctx[(size_t)c * 32768 + i];
  out[i] = s;
}

extern "C" void kernel_launch(void* const* d_in, const int* in_sizes, int n_in,
                              void* d_out, int out_size, void* d_ws, size_t ws_size,
                              hipStream_t stream) {
  const float* query = (const float*)d_in[0];
  const float* value = (const float*)d_in[1];
  const float* Wq    = (const float*)d_in[2];
  const float* Wv    = (const float*)d_in[3];
  const float* v     = (const float*)d_in[4];
  const float* bias  = (const float*)d_in[5];
  const float* g     = (const float*)d_in[6];
  const unsigned char* mask = (const unsigned char*)d_in[7];
  float* out = (float*)d_out;

  char* ws = (char*)d_ws;
  unsigned short* Wvb = (unsigned short*)ws;                        // 2 MB
  float* pqb    = (float*)(ws + 2097152);                           // 128 KB
  float* nv     = pqb + 32 * 1024;                                  // 4 KB
  float* part   = nv + 1024;                                        // 1 MB
  float* scores = part + 4 * MROWS;                                 // 256 KB
  float* pctx   = scores + MROWS;                                   // 4 MB

  k_pre<<<1537, 256, 0, stream>>>(Wv, Wvb, v, g, nv, query, Wq, bias, pqb);
  k_gemm<<<1024, 512, 0, stream>>>(value, Wvb, pqb, nv, part);
  k_softmax<<<32, 256, 0, stream>>>(part, mask, scores, out + 32768);
  dim3 gf(32, 16);
  k_ctx<<<gf, 256, 0, stream>>>(value, scores, pctx);
  k_ctx_reduce<<<128, 256, 0, stream>>>(pctx, out);
}

// Round 13
// 249.962 us; speedup vs baseline: 1.0372x; 1.0372x over previous
//
#include <hip/hip_runtime.h>
#include <hip/hip_bf16.h>
#include <stdint.h>

#define SEQ 2048
#define BAT 32
#define EDIM 1024
#define MROWS (SEQ*BAT)   // 65536

typedef __bf16 bf16x8 __attribute__((ext_vector_type(8)));
typedef float f32x4 __attribute__((ext_vector_type(4)));
typedef unsigned short u16x8 __attribute__((ext_vector_type(8)));

typedef __attribute__((address_space(3))) unsigned int lds_uint;
typedef const __attribute__((address_space(1))) unsigned int glb_uint;

__device__ __forceinline__ void async16(void* lds, const void* g) {
  __builtin_amdgcn_global_load_lds((glb_uint*)g, (lds_uint*)lds, 16, 0, 0);
}

// hardware cvt (RNE): compiler emits v_cvt_pk_bf16_f32 pairs
__device__ __forceinline__ u16x8 cvt8(float4 a, float4 b) {
  bf16x8 r;
  r[0] = (__bf16)a.x; r[1] = (__bf16)a.y; r[2] = (__bf16)a.z; r[3] = (__bf16)a.w;
  r[4] = (__bf16)b.x; r[5] = (__bf16)b.y; r[6] = (__bf16)b.z; r[7] = (__bf16)b.w;
  return __builtin_bit_cast(u16x8, r);
}

// fast tanh: (e^{2x}-1)/(e^{2x}+1), clamped; ~7 VALU ops vs ~25 for ocml tanhf
__device__ __forceinline__ float fast_tanh(float x) {
  float xc = fminf(fmaxf(x, -9.f), 9.f);
  float e = __expf(2.f * xc);
  return (e - 1.f) * __builtin_amdgcn_rcpf(e + 1.f);
}

// ---------------- Kernel PRE: fused {Wv cvt | nv | pqb} by blockIdx role ----------
__global__ void k_pre(const float* __restrict__ Wv, unsigned short* __restrict__ Wvb,
                      const float* __restrict__ v, const float* __restrict__ g,
                      float* __restrict__ nv,
                      const float* __restrict__ query, const float* __restrict__ Wq,
                      const float* __restrict__ bias, float* __restrict__ pqb) {
  const int bid = blockIdx.x;
  const int t = threadIdx.x;

  if (bid < 512) {                      // ---- Wv convert ----
    long long i = (long long)bid * 256 + t;   // 131072 chunks of 8
    const float4* p = reinterpret_cast<const float4*>(Wv + i * 8);
    *reinterpret_cast<u16x8*>(Wvb + i * 8) = cvt8(p[0], p[1]);
    return;
  }

  if (bid == 512) {                     // ---- nv ----
    __shared__ float red[256];
    float s = 0.f;
    for (int i = t; i < EDIM; i += 256) { float x = v[i]; s += x * x; }
    red[t] = s; __syncthreads();
    for (int o = 128; o > 0; o >>= 1) {
      if (t < o) red[t] += red[t + o];
      __syncthreads();
    }
    float scale = g[0] / sqrtf(red[0]);
    for (int i = t; i < EDIM; i += 256) nv[i] = v[i] * scale;
    return;
  }

  // ---- pqb ----
  __shared__ float wq[1024];
  const int e = bid - 513;
  reinterpret_cast<float4*>(wq)[t] =
      reinterpret_cast<const float4*>(Wq + (size_t)e * EDIM)[t];
  __syncthreads();
  int w = t >> 6, lane = t & 63;
  float be = bias[e];
  for (int bb = 0; bb < 8; ++bb) {
    int b_ = w * 8 + bb;
    const float4* q4 = reinterpret_cast<const float4*>(query + (size_t)b_ * EDIM) + lane * 4;
    const float4* w4 = reinterpret_cast<const float4*>(wq) + lane * 4;
    float s = 0.f;
#pragma unroll
    for (int jj = 0; jj < 4; ++jj) {
      float4 a = q4[jj], c = w4[jj];
      s += a.x * c.x + a.y * c.y + a.z * c.z + a.w * c.w;
    }
#pragma unroll
    for (int m = 32; m > 0; m >>= 1) s += __shfl_xor(s, m);
    if (lane == 0) pqb[(size_t)b_ * EDIM + e] = s + be;
  }
}

// ---------------- Kernel D: 256x256-tile pipelined GEMM, in-kernel fp32->bf16 A ----
// Best measured form (R9/R11): 2-phase schedule, T2 swizzle (conflicts=0), fused
// fp32 A staging in two 16-VGPR halves, async16 B, XCD-chunked grid.
__global__ __launch_bounds__(512, 1) void k_gemm(
    const float* __restrict__ value,        // [MROWS][1024] fp32
    const unsigned short* __restrict__ Bm,  // [1024][1024] bf16 bits
    const float* __restrict__ pqb,          // [32][1024]
    const float* __restrict__ nv,           // [1024]
    float* __restrict__ part)               // [4][MROWS]
{
  __shared__ char smem[2 * 65536 + 4 * 256 * 4];

  const int tid = threadIdx.x;
  const int lane = tid & 63;
  const int wid = tid >> 6;
  const int wm = wid >> 2;                  // 0..1
  const int wn = wid & 3;                   // 0..3

  const int bid = blockIdx.x;               // 0..1023
  const int xcd = bid & 7;
  const int j = bid >> 3;                   // 0..127
  const int mi_blk = xcd * 32 + (j >> 2);
  const int ni_blk = j & 3;
  const size_t m0 = (size_t)mi_blk * 256;
  const int n0 = ni_blk * 256;

  float* partLds = (float*)(smem + 131072);

  f32x4 acc[8][4];
#pragma unroll
  for (int i = 0; i < 8; ++i)
#pragma unroll
    for (int jj = 0; jj < 4; ++jj) acc[i][jj] = f32x4{0.f, 0.f, 0.f, 0.f};

  // ---- A staging (fp32 -> reg -> cvt -> swizzled ds_write), 2 halves ----
  const int csrc = (tid & 7) ^ ((tid >> 3) & 7);
  const int rowt = tid >> 3;                // 0..63
  const float* gvA[4];
#pragma unroll
  for (int i = 0; i < 4; ++i)
    gvA[i] = value + (m0 + (size_t)(i * 64 + rowt)) * 1024 + (tid & 7) * 8;
  const int dstA0 = rowt * 128 + csrc * 16;  // + c*8192 per chunk

  float4 ar[4];   // ONE shared 16-VGPR staging block; WAR dep stops overlap

  auto loadAh = [&](int h) {
#pragma unroll
    for (int i = 0; i < 2; ++i) {
      int c = 2 * h + i;
      ar[2 * i]     = *reinterpret_cast<const float4*>(gvA[c]);
      ar[2 * i + 1] = *reinterpret_cast<const float4*>(gvA[c] + 4);
      gvA[c] += 64;
    }
  };
  auto writeAh = [&](char* nb, int h) {
#pragma unroll
    for (int i = 0; i < 2; ++i) {
      int c = 2 * h + i;
      *reinterpret_cast<u16x8*>(nb + c * 8192 + dstA0) = cvt8(ar[2 * i], ar[2 * i + 1]);
    }
  };

  // ---- B staging (async16, inverse-swizzled source) ----
  const unsigned short* gB[4];
#pragma unroll
  for (int i = 0; i < 4; ++i)
    gB[i] = Bm + (size_t)(n0 + i * 64 + rowt) * 1024 + csrc * 8;
  const int ldsOffB = 32768 + tid * 16;
  auto stageB = [&](char* sl) {
#pragma unroll
    for (int i = 0; i < 4; ++i) {
      async16(sl + ldsOffB + i * 8192, gB[i]);
      gB[i] += 64;
    }
  };

  // ---- LDS read addressing (conflict-free) ----
  const int rA = lane & 15;
  const int cs0 = (lane >> 4) ^ (lane & 7);
  const int cs1 = cs0 ^ 4;

  char* buf0 = smem;
  char* buf1 = smem + 65536;

  loadAh(0);
  stageB(buf0);
  writeAh(buf0, 0);
  loadAh(1);
  writeAh(buf0, 1);
  __syncthreads();

  auto body = [&](char* cb, char* nb, bool pf) {
    if (pf) loadAh(0);

    // ---- kk = 0 ----
    {
      bf16x8 af[8], bf[4];
#pragma unroll
      for (int mi = 0; mi < 8; ++mi)
        af[mi] = *reinterpret_cast<const bf16x8*>(
            cb + (wm * 128 + mi * 16 + rA) * 128 + cs0 * 16);
#pragma unroll
      for (int nj = 0; nj < 2; ++nj)
        bf[nj] = *reinterpret_cast<const bf16x8*>(
            cb + 32768 + (wn * 64 + nj * 16 + rA) * 128 + cs0 * 16);

      __builtin_amdgcn_s_setprio(1);
#pragma unroll
      for (int mi = 0; mi < 8; ++mi)
#pragma unroll
        for (int nj = 0; nj < 2; ++nj)
          acc[mi][nj] = __builtin_amdgcn_mfma_f32_16x16x32_bf16(af[mi], bf[nj], acc[mi][nj], 0, 0, 0);
      __builtin_amdgcn_s_setprio(0);

      if (pf) stageB(nb);

#pragma unroll
      for (int nj = 2; nj < 4; ++nj)
        bf[nj] = *reinterpret_cast<const bf16x8*>(
            cb + 32768 + (wn * 64 + nj * 16 + rA) * 128 + cs0 * 16);

      __builtin_amdgcn_s_setprio(1);
#pragma unroll
      for (int mi = 0; mi < 8; ++mi)
#pragma unroll
        for (int nj = 2; nj < 4; ++nj)
          acc[mi][nj] = __builtin_amdgcn_mfma_f32_16x16x32_bf16(af[mi], bf[nj], acc[mi][nj], 0, 0, 0);
      __builtin_amdgcn_s_setprio(0);
    }

    if (pf) {
      writeAh(nb, 0);
      loadAh(1);
    }

    // ---- kk = 1 ----
    {
      bf16x8 af[8], bf[4];
#pragma unroll
      for (int mi = 0; mi < 8; ++mi)
        af[mi] = *reinterpret_cast<const bf16x8*>(
            cb + (wm * 128 + mi * 16 + rA) * 128 + cs1 * 16);
#pragma unroll
      for (int nj = 0; nj < 2; ++nj)
        bf[nj] = *reinterpret_cast<const bf16x8*>(
            cb + 32768 + (wn * 64 + nj * 16 + rA) * 128 + cs1 * 16);

      __builtin_amdgcn_s_setprio(1);
#pragma unroll
      for (int mi = 0; mi < 8; ++mi)
#pragma unroll
        for (int nj = 0; nj < 2; ++nj)
          acc[mi][nj] = __builtin_amdgcn_mfma_f32_16x16x32_bf16(af[mi], bf[nj], acc[mi][nj], 0, 0, 0);
      __builtin_amdgcn_s_setprio(0);

#pragma unroll
      for (int nj = 2; nj < 4; ++nj)
        bf[nj] = *reinterpret_cast<const bf16x8*>(
            cb + 32768 + (wn * 64 + nj * 16 + rA) * 128 + cs1 * 16);

      __builtin_amdgcn_s_setprio(1);
#pragma unroll
      for (int mi = 0; mi < 8; ++mi)
#pragma unroll
        for (int nj = 2; nj < 4; ++nj)
          acc[mi][nj] = __builtin_amdgcn_mfma_f32_16x16x32_bf16(af[mi], bf[nj], acc[mi][nj], 0, 0, 0);
      __builtin_amdgcn_s_setprio(0);
    }

    if (pf) writeAh(nb, 1);
    __syncthreads();
  };

#pragma unroll 1
  for (int tt = 0; tt < 8; ++tt) {
    body(buf0, buf1, true);
    body(buf1, buf0, tt < 7);
  }

  // Epilogue
  const int cgrp = lane >> 4;
  const int ccol = lane & 15;
  float nve[4];
#pragma unroll
  for (int nj = 0; nj < 4; ++nj) nve[nj] = nv[n0 + wn * 64 + nj * 16 + ccol];

#pragma unroll
  for (int mi = 0; mi < 8; ++mi) {
#pragma unroll
    for (int r = 0; r < 4; ++r) {
      int rloc = wm * 128 + mi * 16 + cgrp * 4 + r;
      int b_ = rloc & 31;
      const float* pq = pqb + (size_t)b_ * EDIM + n0 + wn * 64 + ccol;
      float s = 0.f;
#pragma unroll
      for (int nj = 0; nj < 4; ++nj)
        s += nve[nj] * fast_tanh(acc[mi][nj][r] + pq[nj * 16]);
      s += __shfl_xor(s, 1);
      s += __shfl_xor(s, 2);
      s += __shfl_xor(s, 4);
      s += __shfl_xor(s, 8);
      if (ccol == 0) partLds[wn * 256 + rloc] = s;
    }
  }
  __syncthreads();
  if (tid < 256)
    part[(size_t)ni_blk * MROWS + m0 + tid] =
        partLds[tid] + partLds[256 + tid] + partLds[512 + tid] + partLds[768 + tid];
}

// ---------------- Kernel E: reduce 4 chunks + mask + softmax over s ----------------
__global__ void k_softmax(const float* __restrict__ part,          // [4][MROWS]
                          const unsigned char* __restrict__ mask,  // [S][B]
                          float* __restrict__ scores,              // [MROWS]
                          float* __restrict__ out_attn)            // d_out + 32768
{
  int b_ = blockIdx.x;
  int t = threadIdx.x;
  __shared__ float red[256];
  float sc[8];
  float mx = -1e30f;
#pragma unroll
  for (int i = 0; i < 8; ++i) {
    int s_ = t + i * 256;
    size_t r = (size_t)s_ * BAT + b_;
    float v = 0.f;
#pragma unroll
    for (int c = 0; c < 4; ++c) v += part[(size_t)c * MROWS + r];
    if (mask[r]) v = -1e30f;
    sc[i] = v;
    mx = fmaxf(mx, v);
  }
  red[t] = mx; __syncthreads();
  for (int o = 128; o > 0; o >>= 1) {
    if (t < o) red[t] = fmaxf(red[t], red[t + o]);
    __syncthreads();
  }
  mx = red[0];
  __syncthreads();
  float sum = 0.f;
#pragma unroll
  for (int i = 0; i < 8; ++i) { sc[i] = expf(sc[i] - mx); sum += sc[i]; }
  red[t] = sum; __syncthreads();
  for (int o = 128; o > 0; o >>= 1) {
    if (t < o) red[t] += red[t + o];
    __syncthreads();
  }
  float inv = 1.f / red[0];
#pragma unroll
  for (int i = 0; i < 8; ++i) {
    int s_ = t + i * 256;
    size_t r = (size_t)s_ * BAT + b_;
    float w = sc[i] * inv;
    scores[r] = w;
    out_attn[r] = w;
    out_attn[MROWS + r] = w;
  }
}

// ---------------- Kernel F: context partials (fp32 value, L3-resident) ----------
__global__ void k_ctx(const float* __restrict__ value,   // [MROWS][1024] fp32
                      const float* __restrict__ scores,  // [MROWS]
                      float* __restrict__ pctx)          // [32][BAT][1024]
{
  int b_ = blockIdx.x;   // 0..31
  int sch = blockIdx.y;  // 0..15
  int t = threadIdx.x;
  int d8 = t & 127;
  int sr = t >> 7;       // 0..1
  float acc[8];
#pragma unroll
  for (int j = 0; j < 8; ++j) acc[j] = 0.f;
  int s0 = sch * 128;
  for (int i = 0; i < 64; ++i) {
    int s_ = s0 + i * 2 + sr;
    size_t r = (size_t)s_ * BAT + b_;
    float w = scores[r];
    const float4* p = reinterpret_cast<const float4*>(value + r * 1024 + d8 * 8);
    float4 a = p[0], b = p[1];
    acc[0] += w * a.x; acc[1] += w * a.y; acc[2] += w * a.z; acc[3] += w * a.w;
    acc[4] += w * b.x; acc[5] += w * b.y; acc[6] += w * b.z; acc[7] += w * b.w;
  }
  float* dst = pctx + ((size_t)(sch * 2 + sr) * BAT + b_) * 1024 + d8 * 8;
#pragma unroll
  for (int j = 0; j < 8; ++j) dst[j] = acc[j];
}

// ---------------- Kernel G: final context reduce (32 chunks) ----------------
__global__ void k_ctx_reduce(const float* __restrict__ pctx, float* __restrict__ out) {
  int i = blockIdx.x * 256 + threadIdx.x;  // 0..32767
  float s = 0.f;
#pragma unroll
  for (int c = 0; c < 32; ++c) s += pctx[(size_t)c * 32768 + i];
  out[i] = s;
}

extern "C" void kernel_launch(void* const* d_in, const int* in_sizes, int n_in,
                              void* d_out, int out_size, void* d_ws, size_t ws_size,
                              hipStream_t stream) {
  const float* query = (const float*)d_in[0];
  const float* value = (const float*)d_in[1];
  const float* Wq    = (const float*)d_in[2];
  const float* Wv    = (const float*)d_in[3];
  const float* v     = (const float*)d_in[4];
  const float* bias  = (const float*)d_in[5];
  const float* g     = (const float*)d_in[6];
  const unsigned char* mask = (const unsigned char*)d_in[7];
  float* out = (float*)d_out;

  char* ws = (char*)d_ws;
  unsigned short* Wvb = (unsigned short*)ws;                        // 2 MB
  float* pqb    = (float*)(ws + 2097152);                           // 128 KB
  float* nv     = pqb + 32 * 1024;                                  // 4 KB
  float* part   = nv + 1024;                                        // 1 MB
  float* scores = part + 4 * MROWS;                                 // 256 KB
  float* pctx   = scores + MROWS;                                   // 4 MB

  k_pre<<<1537, 256, 0, stream>>>(Wv, Wvb, v, g, nv, query, Wq, bias, pqb);
  k_gemm<<<1024, 512, 0, stream>>>(value, Wvb, pqb, nv, part);
  k_softmax<<<32, 256, 0, stream>>>(part, mask, scores, out + 32768);
  dim3 gf(32, 16);
  k_ctx<<<gf, 256, 0, stream>>>(value, scores, pctx);
  k_ctx_reduce<<<128, 256, 0, stream>>>(pctx, out);
}